// Round 29
// baseline (197.256 us; speedup 1.0000x reference)
//
#include <hip/hip_runtime.h>

typedef __attribute__((ext_vector_type(4))) float float4v;
typedef __attribute__((ext_vector_type(8))) short short8;
typedef __attribute__((ext_vector_type(4))) float f32x4;

// B=64, L=2048, E=512, Q=256; M = 131072, K = 512, N = 512
#define MTOT (64 * 2048)

__device__ __forceinline__ unsigned short f2bf(float f) {
    unsigned int u = __float_as_uint(f);
    u += 0x7fffu + ((u >> 16) & 1u);   // RNE round to bf16
    return (unsigned short)(u >> 16);
}

// Wt[e][c] = bf16(W1[c][e]) via LDS 32x32 tile transpose. Also zeroes
// ctxraw (128 floats/block) and S (block 0).
__global__ __launch_bounds__(256)
void prep_wt_kernel(const float* __restrict__ W1, unsigned short* __restrict__ Wt,
                    float* __restrict__ ctxraw, float* __restrict__ S) {
    __shared__ float t[32][33];
    int blk = blockIdx.x;
    if (threadIdx.x < 128) ctxraw[blk * 128 + threadIdx.x] = 0.f;
    if (blk == 0 && threadIdx.x >= 128 && threadIdx.x < 192) S[threadIdx.x - 128] = 0.f;
    int bx = blk & 15;           // c tile
    int by = blk >> 4;           // e tile
    int tx = threadIdx.x & 31;
    int ty = threadIdx.x >> 5;   // 0..7
    #pragma unroll
    for (int i = 0; i < 4; ++i)
        t[ty + 8 * i][tx] = W1[(bx * 32 + ty + 8 * i) * 512 + by * 32 + tx];
    __syncthreads();
    #pragma unroll
    for (int i = 0; i < 4; ++i)
        Wt[(by * 32 + ty + 8 * i) * 512 + bx * 32 + tx] = f2bf(t[tx][ty + 8 * i]);
}

// Race-free parallel qc: 256 blocks = (b, e-quarter of 128 cols).
__global__ __launch_bounds__(256)
void prep_qc_kernel(const float* __restrict__ query, const float* __restrict__ W1,
                    const float* __restrict__ b1, float* __restrict__ qc) {
    __shared__ float part[128];
    int blk = blockIdx.x;
    int b = blk >> 2;
    int e = (blk & 3) * 128 + (threadIdx.x & 127);
    int qh = threadIdx.x >> 7;
    const float* w = W1 + (512 + qh * 128) * 512;
    const float* qv = query + b * 256 + qh * 128;
    float acc = 0.f;
    #pragma unroll 8
    for (int q = 0; q < 128; ++q)
        acc += qv[q] * w[q * 512 + e];
    if (qh) part[threadIdx.x & 127] = acc;
    __syncthreads();
    if (!qh) qc[b * 512 + e] = b1[e] + acc + part[threadIdx.x & 127];
}

// Fused gemm with B READ DIRECTLY FROM L2 (Wt = 512KB, L2/L1-resident;
// guide common-mistake #7: don't LDS-stage cache-fitting data). LDS holds
// only the A tile (4 x 8KB slots, phase-parity pairs) + reduce buffers.
// Phase p: {KCOMP x2 (A from LDS, B via global_load_dwordx4) -> fence ->
// ALOAD x2 (A prefetch AFTER B loads, so in-order vmcnt retirement never
// stalls a B-wait on HBM) -> CVTW x2 into pair (p+1)&1 -> lgkm -> barrier}.
// ONE barrier/phase (pair parity removes the WAR barrier). LDS traffic
// per phase drops 336KB -> 144KB; barriers 16 -> 9 per tile.
__global__ __launch_bounds__(1024)
void gemm_fused_kernel(const float* __restrict__ A,             // encoded [M][512] f32
                       const unsigned short* __restrict__ Wt,   // [512 n][512 k] bf16
                       const float* __restrict__ qc,            // [64][512]
                       const float* __restrict__ v,             // [512]
                       const int* __restrict__ length,          // [64]
                       float* __restrict__ att,                 // [M] raw w out
                       float* __restrict__ ctxraw,              // [64][512] accum
                       float* __restrict__ S)                   // [64] sum accum
{
    int bm = blockIdx.x;           // 0..1023 row tile
    int b = bm >> 4;
    int len = length[b];
    int l0 = (bm & 15) * 128;
    if (l0 >= len) return;         // fully-masked tile

    __shared__ unsigned short As[4 * 4096];   // 4 x 8KB slots (2 pairs)
    __shared__ float lred[128][8];
    __shared__ float wbuf[128];

    int tid = threadIdx.x;
    int lane = tid & 63;
    int w = tid >> 6;              // 0..15
    int wm = w >> 3, wn = w & 7;   // 2 x 8 wave grid; wave tile 64x64
    long row0 = (long)bm * 128;

    // --- A reg-staging: thread -> row r = tid>>3, k-eighth e8 = tid&7 (16B) ---
    int ar_r = tid >> 3;
    int ar_e = tid & 7;
    const char* gAr = (const char*)A + (row0 + ar_r) * 2048 + ar_e * 16;
    int awr = ar_r * 64 + ((ar_e * 8) ^ (((ar_r >> 1) & 3) << 4));

    // --- B fragment global bases (L2-hot): ni -> cols wn*64+ni*16+(lane&15),
    //     k-slice (lane>>4)*8; step t adds t*64 bytes ---
    const char* gBf[4];
    #pragma unroll
    for (int ni = 0; ni < 4; ++ni)
        gBf[ni] = (const char*)Wt
                + (long)(wn * 64 + ni * 16 + (lane & 15)) * 1024
                + (lane >> 4) * 16;

    // --- A fragment read byte offsets (within one 8KB slot) ---
    int aoff[4];
    int kb = 16 * (lane >> 4);
    #pragma unroll
    for (int mi = 0; mi < 4; ++mi) {
        int ar = wm * 64 + (lane & 15) + mi * 16;
        aoff[mi] = ar * 64 + (kb ^ (((ar >> 1) & 3) << 4));
    }

    f32x4 acc[4][4] = {};
    float4v Pa, Pb, Pc, Pd;        // A reg pairs (even/odd phase)

#define ALOAD(t_, P_) do { P_ = *(const float4v*)(gAr + (t_) * 128); } while (0)

#define CVTW(P_, sW) do {                                                    \
    union { unsigned int u[2]; unsigned long long ll; } pk_;                 \
    pk_.u[0] = (unsigned int)f2bf(P_[0]) | ((unsigned int)f2bf(P_[1]) << 16); \
    pk_.u[1] = (unsigned int)f2bf(P_[2]) | ((unsigned int)f2bf(P_[3]) << 16); \
    *(unsigned long long*)((char*)As + (sW) * 8192 + awr) = pk_.ll;          \
} while (0)

#define KCOMP(sA, t_) do {                                                   \
    const char* as_ = (const char*)As + (sA) * 8192;                         \
    short8 af_[4];                                                           \
    _Pragma("unroll")                                                        \
    for (int mi = 0; mi < 4; ++mi) af_[mi] = *(const short8*)(as_ + aoff[mi]); \
    _Pragma("unroll")                                                        \
    for (int ni = 0; ni < 4; ++ni) {                                         \
        short8 bf_ = *(const short8*)(gBf[ni] + (t_) * 64);                  \
        _Pragma("unroll")                                                    \
        for (int mi = 0; mi < 4; ++mi)                                       \
            acc[mi][ni] = __builtin_amdgcn_mfma_f32_16x16x32_bf16(af_[mi], bf_, acc[mi][ni], 0, 0, 0); \
    }                                                                        \
} while (0)

// phase p: steps 2p,2p+1 from As pair p&1 (+ B from L2); fence; prefetch
// A(2p+4),A(2p+5); CVTW A(2p+2),A(2p+3) into pair (p+1)&1; lgkm; barrier.
#define PHASE(p, PI0, PI1, PC0, PC1, AISS) do {                              \
    KCOMP(2*((p)&1),     2*(p));                                             \
    KCOMP(2*((p)&1) + 1, 2*(p)+1);                                           \
    asm volatile("" ::: "memory");                                           \
    if (AISS) { ALOAD(2*(p)+4, PI0); ALOAD(2*(p)+5, PI1); }                  \
    CVTW(PC0, 2*(((p)+1)&1));                                                \
    CVTW(PC1, 2*(((p)+1)&1) + 1);                                            \
    asm volatile("s_waitcnt lgkmcnt(0)" ::: "memory");                       \
    __builtin_amdgcn_s_barrier();                                            \
    asm volatile("" ::: "memory");                                           \
} while (0)

    // prologue: A(0..3) loaded; publish pair 0 (slots 0,1)
    ALOAD(0, Pa);
    ALOAD(1, Pb);
    ALOAD(2, Pc);
    ALOAD(3, Pd);
    CVTW(Pa, 0);
    CVTW(Pb, 1);
    asm volatile("s_waitcnt lgkmcnt(0)" ::: "memory");
    __builtin_amdgcn_s_barrier();
    asm volatile("" ::: "memory");

    PHASE(0, Pa, Pb, Pc, Pd, 1);   // CVTW A2,A3 -> pair1 ; load A4,A5
    PHASE(1, Pc, Pd, Pa, Pb, 1);   // CVTW A4,A5 -> pair0 ; load A6,A7
    PHASE(2, Pa, Pb, Pc, Pd, 1);
    PHASE(3, Pc, Pd, Pa, Pb, 1);
    PHASE(4, Pa, Pb, Pc, Pd, 1);
    PHASE(5, Pc, Pd, Pa, Pb, 1);   // load A14,A15 -> Pc,Pd
    PHASE(6, Pa, Pb, Pc, Pd, 0);   // CVTW A14,A15 -> pair1
    KCOMP(2, 14);                  // phase 7: steps 14,15 from pair1
    KCOMP(3, 15);

    // epilogue: u = tanh(acc + qc), per-wave 64-col partial via 16-lane
    // reduce, then in-block reduce over the 8 wn waves.
    const float* qcb = qc + b * 512;
    float vcol[4], qcol[4];
    #pragma unroll
    for (int ni = 0; ni < 4; ++ni) {
        int c = wn * 64 + ni * 16 + (lane & 15);
        vcol[ni] = v[c];
        qcol[ni] = qcb[c];
    }
    #pragma unroll
    for (int mi = 0; mi < 4; ++mi) {
        #pragma unroll
        for (int j2 = 0; j2 < 4; ++j2) {
            float s = 0.f;
            #pragma unroll
            for (int ni = 0; ni < 4; ++ni) {
                float xx = acc[mi][ni][j2] + qcol[ni];
                float e2 = __expf(2.0f * xx);
                float tt = 1.0f - 2.0f * __builtin_amdgcn_rcpf(e2 + 1.0f);
                s += tt * vcol[ni];
            }
            s += __shfl_xor(s, 1);
            s += __shfl_xor(s, 2);
            s += __shfl_xor(s, 4);
            s += __shfl_xor(s, 8);
            if ((lane & 15) == 0)
                lred[wm * 64 + mi * 16 + 4 * (lane >> 4) + j2][wn] = s;
        }
    }
    __syncthreads();

    // fused: w = exp(logit) (0 beyond length), raw w -> att, sum -> S[b]
    if (tid < 128) {
        float lg = 0.f;
        #pragma unroll
        for (int q = 0; q < 8; ++q) lg += lred[tid][q];
        float wf = (l0 + tid < len) ? __expf(lg) : 0.f;
        att[row0 + tid] = wf;
        wbuf[tid] = wf;
        float s = wf;
        #pragma unroll
        for (int m = 32; m; m >>= 1) s += __shfl_xor(s, m);
        if ((tid & 63) == 0) atomicAdd(&S[b], s);
    }
    __syncthreads();

    // fused ctx: thread covers e = tid&511, l-half = tid>>9 (L2-hot A tile)
    {
        int e = tid & 511;
        int lh = tid >> 9;                 // 0 or 1
        const float* encb = A + (row0 + lh * 64) * 512 + e;
        const float* wb = &wbuf[lh * 64];
        float c = 0.f;
        #pragma unroll 4
        for (int l = 0; l < 64; ++l)
            c += wb[l] * encb[l * 512];
        atomicAdd(&ctxraw[b * 512 + e], c);
    }
}

// normalize: att[l] = (l<len) ? w[l]/S[b] : 0 ; ctx = ctxraw/S[b]
__global__ void norm_kernel(const float* __restrict__ S, const int* __restrict__ length,
                            const float* __restrict__ ctxraw,
                            float* __restrict__ att, float* __restrict__ ctx) {
    int b = blockIdx.x;
    int tid = threadIdx.x;     // 256
    float inv = 1.0f / S[b];
    ctx[b * 512 + tid] = ctxraw[b * 512 + tid] * inv;
    ctx[b * 512 + 256 + tid] = ctxraw[b * 512 + 256 + tid] * inv;
    int len = length[b];
    float* ab = att + b * 2048;
    #pragma unroll
    for (int i = 0; i < 8; ++i) {
        int l = tid + i * 256;
        float wv = ab[l];
        ab[l] = (l < len) ? wv * inv : 0.f;
    }
}

extern "C" void kernel_launch(void* const* d_in, const int* in_sizes, int n_in,
                              void* d_out, int out_size, void* d_ws, size_t ws_size,
                              hipStream_t stream) {
    const float* enc    = (const float*)d_in[0];   // [64,2048,512]
    const float* query  = (const float*)d_in[1];   // [64,256]
    const int*   length = (const int*)d_in[2];     // [64]
    const float* W1     = (const float*)d_in[3];   // [768,512]
    const float* b1     = (const float*)d_in[4];   // [512]
    const float* v      = (const float*)d_in[5];   // [512]

    float* out = (float*)d_out;
    float* ctx = out;                // [64,512]
    float* att = out + 64 * 512;     // [64,2048]

    char* ws = (char*)d_ws;
    float* qc          = (float*)ws;                               // 128KB
    unsigned short* Wt = (unsigned short*)(ws + 64 * 512 * 4);     // 512KB
    float* ctxraw      = (float*)(ws + 64 * 512 * 4 + 512 * 1024); // 128KB
    float* S           = (float*)(ws + 64 * 512 * 4 + 512 * 1024 + 64 * 512 * 4); // 256B

    prep_wt_kernel<<<256, 256, 0, stream>>>(W1, Wt, ctxraw, S);
    prep_qc_kernel<<<256, 256, 0, stream>>>(query, W1, b1, qc);

    gemm_fused_kernel<<<1024, 1024, 0, stream>>>(enc, Wt, qc, v, length, att, ctxraw, S);

    norm_kernel<<<64, 256, 0, stream>>>(S, length, ctxraw, att, ctx);
}

// Round 30
// 126.148 us; speedup vs baseline: 1.5637x; 1.5637x over previous
//
#include <hip/hip_runtime.h>

typedef __attribute__((ext_vector_type(4))) float float4v;
typedef __attribute__((ext_vector_type(2))) float float2v;
typedef __attribute__((ext_vector_type(8))) short short8;
typedef __attribute__((ext_vector_type(4))) float f32x4;

#define NEGV (-1000000000.0f)

// B=64, L=2048, E=512, Q=256; M = 131072, K = 512, N = 512
#define MTOT (64 * 2048)

__device__ __forceinline__ unsigned short f2bf(float f) {
    unsigned int u = __float_as_uint(f);
    u += 0x7fffu + ((u >> 16) & 1u);   // RNE round to bf16
    return (unsigned short)(u >> 16);
}

// async global->LDS, 16B per lane; LDS dest = wave-uniform base + lane*16
__device__ __forceinline__ void gload_lds16(const void* g, void* l) {
    __builtin_amdgcn_global_load_lds(
        (__attribute__((address_space(1))) unsigned int*)(unsigned long long)(g),
        (__attribute__((address_space(3))) unsigned int*)(unsigned int)(unsigned long long)(l),
        16, 0, 0);
}

// Wt[e][c] = bf16(W1[c][e]) via LDS 32x32 tile transpose. Also zeroes
// ctxraw (128 floats/block) and S (block 0).
__global__ __launch_bounds__(256)
void prep_wt_kernel(const float* __restrict__ W1, unsigned short* __restrict__ Wt,
                    float* __restrict__ ctxraw, float* __restrict__ S) {
    __shared__ float t[32][33];
    int blk = blockIdx.x;
    if (threadIdx.x < 128) ctxraw[blk * 128 + threadIdx.x] = 0.f;
    if (blk == 0 && threadIdx.x >= 128 && threadIdx.x < 192) S[threadIdx.x - 128] = 0.f;
    int bx = blk & 15;           // c tile
    int by = blk >> 4;           // e tile
    int tx = threadIdx.x & 31;
    int ty = threadIdx.x >> 5;   // 0..7
    #pragma unroll
    for (int i = 0; i < 4; ++i)
        t[ty + 8 * i][tx] = W1[(bx * 32 + ty + 8 * i) * 512 + by * 32 + tx];
    __syncthreads();
    #pragma unroll
    for (int i = 0; i < 4; ++i)
        Wt[(by * 32 + ty + 8 * i) * 512 + bx * 32 + tx] = f2bf(t[tx][ty + 8 * i]);
}

// Race-free parallel qc: 256 blocks = (b, e-quarter of 128 cols).
// Thread t: col = eq*128 + (t&127), q-half qh = t>>7; halves combined in LDS.
__global__ __launch_bounds__(256)
void prep_qc_kernel(const float* __restrict__ query, const float* __restrict__ W1,
                    const float* __restrict__ b1, float* __restrict__ qc) {
    __shared__ float part[128];
    int blk = blockIdx.x;
    int b = blk >> 2;
    int e = (blk & 3) * 128 + (threadIdx.x & 127);
    int qh = threadIdx.x >> 7;
    const float* w = W1 + (512 + qh * 128) * 512;
    const float* qv = query + b * 256 + qh * 128;
    float acc = 0.f;
    #pragma unroll 8
    for (int q = 0; q < 128; ++q)
        acc += qv[q] * w[q * 512 + e];
    if (qh) part[threadIdx.x & 127] = acc;
    __syncthreads();
    if (!qh) qc[b * 512 + e] = b1[e] + acc + part[threadIdx.x & 127];
}

// Best-measured fused gemm (R23/R26/R28, ~126.0-126.5us total): BM=128 x
// BN=512, BK=32, 16 waves. TWO K-steps per barrier phase (8 phases), 4-slot
// B ring via global_load_lds (pre-swizzled source), 2-slot As (reg-staged
// f32->bf16), A loads 4 steps ahead (Pa-Pd ring), counted vmcnt(2) per
// phase (never drained mid-loop). Fused epilogue: logits -> w=exp(logit)
// (no max-sub needed: |logit| <= sum|v| ~ 25), raw w -> att, sum -> S[b],
// and ctxraw[b][e] += sum_l w[l]*enc[l][e] from the L2-hot A tile.
// R29 note: B staged via LDS beats B-from-L2 (per-fragment L2 latency on
// the MFMA path regressed 1.6x) -- keep the LDS path.
__global__ __launch_bounds__(1024)
void gemm_fused_kernel(const float* __restrict__ A,             // encoded [M][512] f32
                       const unsigned short* __restrict__ Wt,   // [512 n][512 k] bf16
                       const float* __restrict__ qc,            // [64][512]
                       const float* __restrict__ v,             // [512]
                       const int* __restrict__ length,          // [64]
                       float* __restrict__ att,                 // [M] raw w out
                       float* __restrict__ ctxraw,              // [64][512] accum
                       float* __restrict__ S)                   // [64] sum accum
{
    int bm = blockIdx.x;           // 0..1023 row tile
    int b = bm >> 4;
    int len = length[b];
    int l0 = (bm & 15) * 128;
    if (l0 >= len) return;         // fully-masked tile

    __shared__ char smem[147456];  // 16KB As(2 slots) + 128KB Bs(4 slots)
    unsigned short* As = (unsigned short*)smem;            // 2 x 8 KB
    unsigned short* Bs = (unsigned short*)(smem + 16384);  // 4 x 32 KB ring
    float (*lred)[8] = (float(*)[8])(smem + 16384);        // overlay Bs slot0
    float* wbuf = (float*)(smem + 16384 + 4096);           // overlay Bs slot0

    int tid = threadIdx.x;
    int lane = tid & 63;
    int w = tid >> 6;              // 0..15
    int wm = w >> 3, wn = w & 7;   // 2 x 8 wave grid; wave tile 64x64
    long row0 = (long)bm * 128;

    // --- A reg-staging: thread -> row r = tid>>3, k-eighth e8 = tid&7 (16B) ---
    int ar_r = tid >> 3;
    int ar_e = tid & 7;
    const char* gAr = (const char*)A + (row0 + ar_r) * 2048 + ar_e * 16;
    int awr = ar_r * 64 + ((ar_e * 8) ^ (((ar_r >> 1) & 3) << 4));

    // --- B staging: 2 insts/wave/step; linear LDS dest, pre-swizzled src ---
    int offw = w * 2048 + lane * 16;             // this wave's 2KB of 32KB slot
    const char* gB0;
    const char* gB1;
    {
        int o = offw;
        int r = o >> 6;
        gB0 = (const char*)Wt + r * 1024 + ((o & 63) ^ (((r >> 1) & 3) << 4));
        o = offw + 1024;
        r = o >> 6;
        gB1 = (const char*)Wt + r * 1024 + ((o & 63) ^ (((r >> 1) & 3) << 4));
    }

    // --- fragment read byte offsets ---
    int aoff[4], boff[4];
    int kb = 16 * (lane >> 4);
    #pragma unroll
    for (int mi = 0; mi < 4; ++mi) {
        int ar = wm * 64 + (lane & 15) + mi * 16;
        aoff[mi] = ar * 64 + (kb ^ (((ar >> 1) & 3) << 4));
    }
    #pragma unroll
    for (int ni = 0; ni < 4; ++ni) {
        int br = wn * 64 + (lane & 15) + ni * 16;
        boff[ni] = br * 64 + (kb ^ (((br >> 1) & 3) << 4));
    }

    f32x4 acc[4][4] = {};
    float4v Pa, Pb, Pc, Pd;        // A ring, 4 steps deep

#define ALOAD(t_, P_) do { P_ = *(const float4v*)(gAr + (t_) * 128); } while (0)

#define BISSUE(t_, sI) do {                                                  \
    char* lb_ = (char*)Bs + (sI) * 32768 + offw;                             \
    gload_lds16(gB0 + (t_) * 64, lb_);                                       \
    gload_lds16(gB1 + (t_) * 64, lb_ + 1024);                                \
} while (0)

#define CVTW(P_, sW) do {                                                    \
    union { unsigned int u[2]; unsigned long long ll; } pk_;                 \
    pk_.u[0] = (unsigned int)f2bf(P_[0]) | ((unsigned int)f2bf(P_[1]) << 16); \
    pk_.u[1] = (unsigned int)f2bf(P_[2]) | ((unsigned int)f2bf(P_[3]) << 16); \
    *(unsigned long long*)((char*)As + (sW) * 8192 + awr) = pk_.ll;          \
} while (0)

#define KCOMP(sA, sB) do {                                                   \
    const char* as_ = (const char*)As + (sA) * 8192;                         \
    const char* bs_ = (const char*)Bs + (sB) * 32768;                        \
    short8 af_[4];                                                           \
    _Pragma("unroll")                                                        \
    for (int mi = 0; mi < 4; ++mi) af_[mi] = *(const short8*)(as_ + aoff[mi]); \
    _Pragma("unroll")                                                        \
    for (int ni = 0; ni < 4; ++ni) {                                         \
        short8 bf_ = *(const short8*)(bs_ + boff[ni]);                       \
        _Pragma("unroll")                                                    \
        for (int mi = 0; mi < 4; ++mi)                                       \
            acc[mi][ni] = __builtin_amdgcn_mfma_f32_16x16x32_bf16(af_[mi], bf_, acc[mi][ni], 0, 0, 0); \
    }                                                                        \
} while (0)

// phase p: steps 2p,2p+1. Issue B(2p+2),B(2p+3) then A(2p+4),A(2p+5);
// 2 KCOMPs; barrier (As/Bs readers done); vmcnt(VM) retires everything
// except the 2 new A loads; dual CVTW; lgkm; barrier.
#define PHASE(p, PI0, PI1, PC0, PC1, AISS, VM) do {                          \
    BISSUE(2*(p)+2, (2*(p)+2) & 3);                                          \
    BISSUE(2*(p)+3, (2*(p)+3) & 3);                                          \
    if (AISS) { ALOAD(2*(p)+4, PI0); ALOAD(2*(p)+5, PI1); }                  \
    KCOMP(0, (2*(p)) & 3);                                                   \
    KCOMP(1, (2*(p)+1) & 3);                                                 \
    asm volatile("" ::: "memory");                                           \
    __builtin_amdgcn_s_barrier();                                            \
    asm volatile("s_waitcnt vmcnt(" #VM ")" ::: "memory");                   \
    CVTW(PC0, 0);                                                            \
    CVTW(PC1, 1);                                                            \
    asm volatile("s_waitcnt lgkmcnt(0)" ::: "memory");                       \
    __builtin_amdgcn_s_barrier();                                            \
    asm volatile("" ::: "memory");                                           \
} while (0)

    // prologue: A(0..3) in regs, B(0),B(1) in flight; publish As slots 0,1
    ALOAD(0, Pa);
    ALOAD(1, Pb);
    BISSUE(0, 0);
    BISSUE(1, 1);
    ALOAD(2, Pc);
    ALOAD(3, Pd);
    asm volatile("s_waitcnt vmcnt(2)" ::: "memory");   // A0,A1,B0,B1 done
    CVTW(Pa, 0);
    CVTW(Pb, 1);
    asm volatile("s_waitcnt lgkmcnt(0)" ::: "memory");
    __builtin_amdgcn_s_barrier();
    asm volatile("" ::: "memory");

    PHASE(0, Pa, Pb, Pc, Pd, 1, 2);
    PHASE(1, Pc, Pd, Pa, Pb, 1, 2);
    PHASE(2, Pa, Pb, Pc, Pd, 1, 2);
    PHASE(3, Pc, Pd, Pa, Pb, 1, 2);
    PHASE(4, Pa, Pb, Pc, Pd, 1, 2);
    PHASE(5, Pc, Pd, Pa, Pb, 1, 2);
    PHASE(6, Pa, Pb, Pc, Pd, 0, 0);    // no new A; drain to 0
    KCOMP(0, 2);                       // step 14
    KCOMP(1, 3);                       // step 15

    // epilogue: u = tanh(acc + qc), per-wave 64-col partial via 16-lane
    // reduce, then in-block reduce over 8 wn waves (lred on Bs slot0 —
    // last slot-0 B read was step 12, fenced by phase 6's barriers).
    const float* qcb = qc + b * 512;
    float vcol[4], qcol[4];
    #pragma unroll
    for (int ni = 0; ni < 4; ++ni) {
        int c = wn * 64 + ni * 16 + (lane & 15);
        vcol[ni] = v[c];
        qcol[ni] = qcb[c];
    }
    #pragma unroll
    for (int mi = 0; mi < 4; ++mi) {
        #pragma unroll
        for (int j2 = 0; j2 < 4; ++j2) {
            float s = 0.f;
            #pragma unroll
            for (int ni = 0; ni < 4; ++ni) {
                float xx = acc[mi][ni][j2] + qcol[ni];
                float e2 = __expf(2.0f * xx);
                float tt = 1.0f - 2.0f * __builtin_amdgcn_rcpf(e2 + 1.0f);
                s += tt * vcol[ni];
            }
            s += __shfl_xor(s, 1);
            s += __shfl_xor(s, 2);
            s += __shfl_xor(s, 4);
            s += __shfl_xor(s, 8);
            if ((lane & 15) == 0)
                lred[wm * 64 + mi * 16 + 4 * (lane >> 4) + j2][wn] = s;
        }
    }
    __syncthreads();

    // fused: w = exp(logit) (0 beyond length), raw w -> att, sum -> S[b]
    if (tid < 128) {
        float lg = 0.f;
        #pragma unroll
        for (int q = 0; q < 8; ++q) lg += lred[tid][q];
        float wf = (l0 + tid < len) ? __expf(lg) : 0.f;
        att[row0 + tid] = wf;
        wbuf[tid] = wf;
        float s = wf;
        #pragma unroll
        for (int m = 32; m; m >>= 1) s += __shfl_xor(s, m);
        if ((tid & 63) == 0) atomicAdd(&S[b], s);
    }
    __syncthreads();

    // fused ctx: thread covers e = tid&511, l-half = tid>>9 (L2-hot A tile)
    {
        int e = tid & 511;
        int lh = tid >> 9;                 // 0 or 1
        const float* encb = A + (row0 + lh * 64) * 512 + e;
        const float* wb = &wbuf[lh * 64];
        float c = 0.f;
        #pragma unroll 4
        for (int l = 0; l < 64; ++l)
            c += wb[l] * encb[l * 512];
        atomicAdd(&ctxraw[b * 512 + e], c);
    }
}

// normalize: att[l] = (l<len) ? w[l]/S[b] : 0 ; ctx = ctxraw/S[b]
__global__ void norm_kernel(const float* __restrict__ S, const int* __restrict__ length,
                            const float* __restrict__ ctxraw,
                            float* __restrict__ att, float* __restrict__ ctx) {
    int b = blockIdx.x;
    int tid = threadIdx.x;     // 256
    float inv = 1.0f / S[b];
    ctx[b * 512 + tid] = ctxraw[b * 512 + tid] * inv;
    ctx[b * 512 + 256 + tid] = ctxraw[b * 512 + 256 + tid] * inv;
    int len = length[b];
    float* ab = att + b * 2048;
    #pragma unroll
    for (int i = 0; i < 8; ++i) {
        int l = tid + i * 256;
        float wv = ab[l];
        ab[l] = (l < len) ? wv * inv : 0.f;
    }
}

extern "C" void kernel_launch(void* const* d_in, const int* in_sizes, int n_in,
                              void* d_out, int out_size, void* d_ws, size_t ws_size,
                              hipStream_t stream) {
    const float* enc    = (const float*)d_in[0];   // [64,2048,512]
    const float* query  = (const float*)d_in[1];   // [64,256]
    const int*   length = (const int*)d_in[2];     // [64]
    const float* W1     = (const float*)d_in[3];   // [768,512]
    const float* b1     = (const float*)d_in[4];   // [512]
    const float* v      = (const float*)d_in[5];   // [512]

    float* out = (float*)d_out;
    float* ctx = out;                // [64,512]
    float* att = out + 64 * 512;     // [64,2048]

    char* ws = (char*)d_ws;
    float* qc          = (float*)ws;                               // 128KB
    unsigned short* Wt = (unsigned short*)(ws + 64 * 512 * 4);     // 512KB
    float* ctxraw      = (float*)(ws + 64 * 512 * 4 + 512 * 1024); // 128KB
    float* S           = (float*)(ws + 64 * 512 * 4 + 512 * 1024 + 64 * 512 * 4); // 256B

    prep_wt_kernel<<<256, 256, 0, stream>>>(W1, Wt, ctxraw, S);
    prep_qc_kernel<<<256, 256, 0, stream>>>(query, W1, b1, qc);

    gemm_fused_kernel<<<1024, 1024, 0, stream>>>(enc, Wt, qc, v, length, att, ctxraw, S);

    norm_kernel<<<64, 256, 0, stream>>>(S, length, ctxraw, att, ctx);
}